// Round 7
// baseline (4835.529 us; speedup 1.0000x reference)
//
#include <hip/hip_runtime.h>
#include <stdint.h>

#define B_ 64
#define T_ 2048
#define H_ 256
#define RING 128
#define PAIRS 4

typedef unsigned int u32;
typedef unsigned short u16;
typedef __attribute__((ext_vector_type(8))) short short8;
typedef __attribute__((ext_vector_type(4))) float f32x4;

// LDS tile: 16 rows x 256 bf16, row stride 512B, XOR-swizzle -> conflict-free
// ds_read_b128 at (row=lane&15, slice=(lane>>4)*8)  [verified rounds 4-6]
#define SWZ(row, byte) (((row) * 512) + ((byte) ^ (((row) & 7) << 4)))

static __device__ __forceinline__ u32 cvtpk(float a, float b) {
  u32 d;
  asm("v_cvt_pk_bf16_f32 %0, %1, %2" : "=v"(d) : "v"(a), "v"(b));
  return d;
}
static __device__ __forceinline__ uint4 pack8(float4 a, float4 b) {
  uint4 r;
  r.x = cvtpk(a.x, a.y); r.y = cvtpk(a.z, a.w);
  r.z = cvtpk(b.x, b.y); r.w = cvtpk(b.z, b.w);
  return r;
}
static __device__ __forceinline__ short8 as8(uint4 v) {
  return __builtin_bit_cast(short8, v);
}
// 1 - 2*rcp(e^{2x}+1); ~1ulp f32 << bf16 rounding; saturates correctly.
static __device__ __forceinline__ float fast_tanh(float x) {
  float e = __expf(2.0f * x);
  float r = __builtin_amdgcn_rcpf(e + 1.0f);
  return fmaf(-2.0f, r, 1.0f);
}

// Verified A/B-operand fragment loader for mfma_f32_16x16x32_bf16 [m89/m91].
template <int NQ>
static __device__ __forceinline__ void load_wfrag(const float* W, int qbase, int bl,
                                                  int g, uint4 wf[NQ][8]) {
#pragma unroll
  for (int q = 0; q < NQ; ++q) {
    const float* wr = W + (size_t)((qbase + q) * 16 + bl) * H_ + g * 8;
#pragma unroll
    for (int kc = 0; kc < 8; ++kc) {
      float4 a = *(const float4*)(wr + kc * 32);
      float4 b = *(const float4*)(wr + kc * 32 + 4);
      wf[q][kc] = pack8(a, b);
    }
  }
}

// ---------------- pre-projection (unchanged, verified) ----------------
__global__ __launch_bounds__(256, 2) void pre_mfma(const float* X, const float* W,
                                                   const float* bi, const float* bh,
                                                   float* P, int tpw) {
  __shared__ char sb_[2][8192];
  const int tid = threadIdx.x;
  const int lane = tid & 63, wv = tid >> 6;
  const int bl = lane & 15, g = lane >> 4;

  uint4 wf[4][8];
  load_wfrag<4>(W, wv * 4, bl, g, wf);
  float4 bias[4];
#pragma unroll
  for (int q = 0; q < 4; ++q) {
    const int j0 = (wv * 4 + q) * 16 + g * 4;
    float4 a = *(const float4*)(bi + j0);
    float4 c = *(const float4*)(bh + j0);
    bias[q].x = a.x + c.x; bias[q].y = a.y + c.y;
    bias[q].z = a.z + c.z; bias[q].w = a.w + c.w;
  }

  const size_t row0 = (size_t)blockIdx.x * tpw * 16;
  const int sr = tid >> 4, sc = (tid & 15) * 16;
  float4 s0, s1, s2, s3;
  {
    const float4* xs = (const float4*)(X + (row0 + sr) * H_ + sc);
    s0 = xs[0]; s1 = xs[1]; s2 = xs[2]; s3 = xs[3];
  }

  for (int i = 0; i < tpw; ++i) {
    char* sb = sb_[i & 1];
    *(uint4*)(sb + SWZ(sr, sc * 2)) = pack8(s0, s1);
    *(uint4*)(sb + SWZ(sr, sc * 2 + 16)) = pack8(s2, s3);
    __syncthreads();
    if (i + 1 < tpw) {
      const float4* xn = (const float4*)(X + (row0 + (i + 1) * 16 + sr) * H_ + sc);
      s0 = xn[0]; s1 = xn[1]; s2 = xn[2]; s3 = xn[3];
    }
    uint4 hf[8];
#pragma unroll
    for (int kc = 0; kc < 8; ++kc)
      hf[kc] = *(const uint4*)(sb + SWZ(bl, kc * 64 + g * 16));
    f32x4 acc[4];
#pragma unroll
    for (int q = 0; q < 4; ++q) {
      acc[q] = (f32x4){0.f, 0.f, 0.f, 0.f};
#pragma unroll
      for (int kc = 0; kc < 8; ++kc)
        acc[q] = __builtin_amdgcn_mfma_f32_16x16x32_bf16(as8(wf[q][kc]), as8(hf[kc]),
                                                         acc[q], 0, 0, 0);
    }
#pragma unroll
    for (int q = 0; q < 4; ++q) {
      const int j0 = (wv * 4 + q) * 16 + g * 4;
      float4 o;
      o.x = acc[q][0] + bias[q].x; o.y = acc[q][1] + bias[q].y;
      o.z = acc[q][2] + bias[q].z; o.w = acc[q][3] + bias[q].w;
      *(float4*)(P + (row0 + i * 16 + bl) * H_ + j0) = o;
    }
    __syncthreads();
  }
}

// ---------------- fallback standalone recurrence (round-6, verified) ----------------
__global__ __launch_bounds__(512, 1) void rec_mfma(const float* pre, const float* W,
                                                   float* out) {
  __shared__ char hb_[2][8192];
  const int tid = threadIdx.x;
  const int lane = tid & 63, wv = tid >> 6;
  const int bl = lane & 15, g = lane >> 4;
  const int b0 = blockIdx.x * 16;

  uint4 wf[2][8];
  load_wfrag<2>(W, wv * 2, bl, g, wf);
  {
    uint4 z = make_uint4(0, 0, 0, 0);
    ((uint4*)hb_[0])[tid] = z;
    ((uint4*)hb_[1])[tid] = z;
  }
  const float* prow = pre + (size_t)(b0 + bl) * T_ * H_;
  float* orow = out + (size_t)(b0 + bl) * T_ * H_;
  float4 pr0[2], pr1[2];
#pragma unroll
  for (int q = 0; q < 2; ++q) {
    const int j0 = (wv * 2 + q) * 16 + g * 4;
    pr0[q] = *(const float4*)(prow + 0 * H_ + j0);
    pr1[q] = *(const float4*)(prow + 1 * H_ + j0);
  }
  __syncthreads();

  auto step = [&](int t, float4 (&pr)[2], char* rbuf, char* wbuf) {
    uint4 hf[8];
#pragma unroll
    for (int kc = 0; kc < 8; ++kc)
      hf[kc] = *(const uint4*)(rbuf + SWZ(bl, kc * 64 + g * 16));
    f32x4 accA[2], accB[2];
#pragma unroll
    for (int q = 0; q < 2; ++q) {
      accA[q] = (f32x4){0.f, 0.f, 0.f, 0.f};
      accB[q] = (f32x4){0.f, 0.f, 0.f, 0.f};
#pragma unroll
      for (int kc = 0; kc < 4; ++kc) {
        accA[q] = __builtin_amdgcn_mfma_f32_16x16x32_bf16(as8(wf[q][kc]),
                                                          as8(hf[kc]), accA[q], 0, 0, 0);
        accB[q] = __builtin_amdgcn_mfma_f32_16x16x32_bf16(as8(wf[q][kc + 4]),
                                                          as8(hf[kc + 4]), accB[q], 0, 0, 0);
      }
    }
#pragma unroll
    for (int q = 0; q < 2; ++q) {
      const int j0 = (wv * 2 + q) * 16 + g * 4;
      const float* pq = (const float*)&pr[q];
      float v0 = fast_tanh(accA[q][0] + accB[q][0] + pq[0]);
      float v1 = fast_tanh(accA[q][1] + accB[q][1] + pq[1]);
      float v2 = fast_tanh(accA[q][2] + accB[q][2] + pq[2]);
      float v3 = fast_tanh(accA[q][3] + accB[q][3] + pq[3]);
      uint2 hw; hw.x = cvtpk(v0, v1); hw.y = cvtpk(v2, v3);
      *(uint2*)(wbuf + SWZ(bl, j0 * 2)) = hw;
      float4 o; o.x = v0; o.y = v1; o.z = v2; o.w = v3;
      *(float4*)(orow + (size_t)t * H_ + j0) = o;
      if (t + 2 < T_)
        pr[q] = *(const float4*)(prow + (size_t)(t + 2) * H_ + j0);
    }
    asm volatile("s_waitcnt lgkmcnt(0)" ::: "memory");
    __builtin_amdgcn_s_barrier();
    __builtin_amdgcn_sched_barrier(0);
  };

  for (int t = 0; t < T_; t += 2) {
    step(t, pr0, hb_[0], hb_[1]);
    step(t + 1, pr1, hb_[1], hb_[0]);
  }
}

// ---------------- fused two-layer pipeline ----------------
__global__ void init_flags(u32* f) { f[threadIdx.x] = 0; }  // 256 threads

// blocks 0..3: producers (layer-0 rec, h0 bf16 -> ws ring, release flag)
// blocks 4..7: consumers (c1 = Wih1*h0 + b folded in; h1 rec; h1 -> d_out)
// One-way data flow + bounded backpressure => no deadlock cycle. 8 WGs.
__global__ __launch_bounds__(512, 2) void fused_rec(
    const float* pre0, const float* Whh0, const float* Wih1, const float* Whh1,
    const float* bih1, const float* bhh1, float* out, u16* ring, u32* flags) {
  __shared__ char hb_[2][8192];
  const int tid = threadIdx.x;
  const int lane = tid & 63, wv = tid >> 6;
  const int bl = lane & 15, g = lane >> 4;
  const int pair = blockIdx.x & (PAIRS - 1);
  const bool prod = blockIdx.x < PAIRS;
  const int b0 = pair * 16;
  u32* pf = flags + pair * 32;            // producer progress (release)
  u32* cf = flags + (PAIRS + pair) * 32;  // consumer progress (relaxed)
  u16* rbase = ring + (size_t)pair * RING * (16 * H_);

  {
    uint4 z = make_uint4(0, 0, 0, 0);
    ((uint4*)hb_[0])[tid] = z;
    ((uint4*)hb_[1])[tid] = z;
  }

  if (prod) {
    uint4 wf[2][8];
    load_wfrag<2>(Whh0, wv * 2, bl, g, wf);
    const float* prow = pre0 + (size_t)(b0 + bl) * T_ * H_;
    float4 pr0[2], pr1[2];
#pragma unroll
    for (int q = 0; q < 2; ++q) {
      const int j0 = (wv * 2 + q) * 16 + g * 4;
      pr0[q] = *(const float4*)(prow + 0 * H_ + j0);
      pr1[q] = *(const float4*)(prow + 1 * H_ + j0);
    }
    __syncthreads();

    auto pstep = [&](int t, float4 (&pr)[2], char* rbuf, char* wbuf) {
      uint4 hf[8];
#pragma unroll
      for (int kc = 0; kc < 8; ++kc)
        hf[kc] = *(const uint4*)(rbuf + SWZ(bl, kc * 64 + g * 16));
      f32x4 accA[2], accB[2];
#pragma unroll
      for (int q = 0; q < 2; ++q) {
        accA[q] = (f32x4){0.f, 0.f, 0.f, 0.f};
        accB[q] = (f32x4){0.f, 0.f, 0.f, 0.f};
#pragma unroll
        for (int kc = 0; kc < 4; ++kc) {
          accA[q] = __builtin_amdgcn_mfma_f32_16x16x32_bf16(as8(wf[q][kc]),
                                                            as8(hf[kc]), accA[q], 0, 0, 0);
          accB[q] = __builtin_amdgcn_mfma_f32_16x16x32_bf16(as8(wf[q][kc + 4]),
                                                            as8(hf[kc + 4]), accB[q], 0, 0, 0);
        }
      }
      u16* rslot = rbase + (size_t)(t & (RING - 1)) * (16 * H_) + bl * H_;
#pragma unroll
      for (int q = 0; q < 2; ++q) {
        const int j0 = (wv * 2 + q) * 16 + g * 4;
        const float* pq = (const float*)&pr[q];
        float v0 = fast_tanh(accA[q][0] + accB[q][0] + pq[0]);
        float v1 = fast_tanh(accA[q][1] + accB[q][1] + pq[1]);
        float v2 = fast_tanh(accA[q][2] + accB[q][2] + pq[2]);
        float v3 = fast_tanh(accA[q][3] + accB[q][3] + pq[3]);
        uint2 hw; hw.x = cvtpk(v0, v1); hw.y = cvtpk(v2, v3);
        *(uint2*)(wbuf + SWZ(bl, j0 * 2)) = hw;   // h0 for step t+1 (LDS)
        *(uint2*)(rslot + j0) = hw;               // h0 to ring (global)
        if (t + 2 < T_)
          pr[q] = *(const float4*)(prow + (size_t)(t + 2) * H_ + j0);
      }
      if ((t & 15) == 15) {
        // all waves drain stores, barrier, then one lane release-publishes
        asm volatile("s_waitcnt vmcnt(0) lgkmcnt(0)" ::: "memory");
        __builtin_amdgcn_s_barrier();
        if (tid == 0)
          __hip_atomic_store(pf, (u32)(t + 1), __ATOMIC_RELEASE, __HIP_MEMORY_SCOPE_AGENT);
        if (t + 1 < T_) {  // backpressure: don't lap the consumer
          int needed = t + 25 - RING;
          if (needed > 0)
            while ((int)__hip_atomic_load(cf, __ATOMIC_RELAXED, __HIP_MEMORY_SCOPE_AGENT) < needed)
              __builtin_amdgcn_s_sleep(16);
        }
      } else {
        asm volatile("s_waitcnt lgkmcnt(0)" ::: "memory");
        __builtin_amdgcn_s_barrier();
      }
      __builtin_amdgcn_sched_barrier(0);
    };

    for (int t = 0; t < T_; t += 2) {
      pstep(t, pr0, hb_[0], hb_[1]);
      pstep(t + 1, pr1, hb_[1], hb_[0]);
    }
  } else {
    uint4 wfi[2][8], wfh[2][8];
    load_wfrag<2>(Wih1, wv * 2, bl, g, wfi);
    load_wfrag<2>(Whh1, wv * 2, bl, g, wfh);
    float4 cb[2];
#pragma unroll
    for (int q = 0; q < 2; ++q) {
      const int j0 = (wv * 2 + q) * 16 + g * 4;
      float4 a = *(const float4*)(bih1 + j0);
      float4 c = *(const float4*)(bhh1 + j0);
      cb[q].x = a.x + c.x; cb[q].y = a.y + c.y;
      cb[q].z = a.z + c.z; cb[q].w = a.w + c.w;
    }
    float* orow = out + (size_t)(b0 + bl) * T_ * H_;
    const u16* rrd = rbase + bl * H_ + g * 8;
    __syncthreads();

    u32 kf = 0;
    {  // prologue: wait for producer, build c1[0] from ring slot 0
      while (__hip_atomic_load(pf, __ATOMIC_ACQUIRE, __HIP_MEMORY_SCOPE_AGENT) < 32u)
        __builtin_amdgcn_s_sleep(16);
      kf = 32;
    }
    float4 c1A[2], c1B[2];
    {
      uint4 h0p[8];
#pragma unroll
      for (int kc = 0; kc < 8; ++kc)
        h0p[kc] = *(const uint4*)(rrd + (size_t)0 * (16 * H_) + kc * 32);
#pragma unroll
      for (int q = 0; q < 2; ++q) {
        f32x4 aA = (f32x4){0.f, 0.f, 0.f, 0.f}, aB = (f32x4){0.f, 0.f, 0.f, 0.f};
#pragma unroll
        for (int kc = 0; kc < 4; ++kc) {
          aA = __builtin_amdgcn_mfma_f32_16x16x32_bf16(as8(wfi[q][kc]), as8(h0p[kc]), aA, 0, 0, 0);
          aB = __builtin_amdgcn_mfma_f32_16x16x32_bf16(as8(wfi[q][kc + 4]), as8(h0p[kc + 4]), aB, 0, 0, 0);
        }
        c1A[q].x = aA[0] + aB[0] + cb[q].x; c1A[q].y = aA[1] + aB[1] + cb[q].y;
        c1A[q].z = aA[2] + aB[2] + cb[q].z; c1A[q].w = aA[3] + aB[3] + cb[q].w;
      }
    }

    auto cstep = [&](int t, float4 (&c1u)[2], float4 (&c1n)[2], char* rbuf, char* wbuf) {
      if ((t & 15) == 0) {  // chunk gate: ensure ring slots through t+16 published
        u32 tgt = (t + 32 < T_) ? (u32)(t + 32) : (u32)T_;
        if (kf < tgt) {
          while (__hip_atomic_load(pf, __ATOMIC_ACQUIRE, __HIP_MEMORY_SCOPE_AGENT) < tgt)
            __builtin_amdgcn_s_sleep(16);
          kf = tgt;
        }
      }
      uint4 h0f[8];  // issue early; consumed at c1-build below (same step)
      {
        const u16* rs = rrd + (size_t)((t + 1) & (RING - 1)) * (16 * H_);
        if (t + 1 < T_) {
#pragma unroll
          for (int kc = 0; kc < 8; ++kc)
            h0f[kc] = *(const uint4*)(rs + kc * 32);
        }
      }
      uint4 hf[8];
#pragma unroll
      for (int kc = 0; kc < 8; ++kc)
        hf[kc] = *(const uint4*)(rbuf + SWZ(bl, kc * 64 + g * 16));
      f32x4 accA[2], accB[2];
#pragma unroll
      for (int q = 0; q < 2; ++q) {
        accA[q] = (f32x4){0.f, 0.f, 0.f, 0.f};
        accB[q] = (f32x4){0.f, 0.f, 0.f, 0.f};
#pragma unroll
        for (int kc = 0; kc < 4; ++kc) {
          accA[q] = __builtin_amdgcn_mfma_f32_16x16x32_bf16(as8(wfh[q][kc]),
                                                            as8(hf[kc]), accA[q], 0, 0, 0);
          accB[q] = __builtin_amdgcn_mfma_f32_16x16x32_bf16(as8(wfh[q][kc + 4]),
                                                            as8(hf[kc + 4]), accB[q], 0, 0, 0);
        }
      }
#pragma unroll
      for (int q = 0; q < 2; ++q) {
        const int j0 = (wv * 2 + q) * 16 + g * 4;
        const float* pq = (const float*)&c1u[q];
        float v0 = fast_tanh(accA[q][0] + accB[q][0] + pq[0]);
        float v1 = fast_tanh(accA[q][1] + accB[q][1] + pq[1]);
        float v2 = fast_tanh(accA[q][2] + accB[q][2] + pq[2]);
        float v3 = fast_tanh(accA[q][3] + accB[q][3] + pq[3]);
        uint2 hw; hw.x = cvtpk(v0, v1); hw.y = cvtpk(v2, v3);
        *(uint2*)(wbuf + SWZ(bl, j0 * 2)) = hw;     // h1 for step t+1
        float4 o; o.x = v0; o.y = v1; o.z = v2; o.w = v3;
        *(float4*)(orow + (size_t)t * H_ + j0) = o; // final output
      }
      // build c1 for t+1 (h0f arrives under the chain above)
#pragma unroll
      for (int q = 0; q < 2; ++q) {
        f32x4 aA = (f32x4){0.f, 0.f, 0.f, 0.f}, aB = (f32x4){0.f, 0.f, 0.f, 0.f};
#pragma unroll
        for (int kc = 0; kc < 4; ++kc) {
          aA = __builtin_amdgcn_mfma_f32_16x16x32_bf16(as8(wfi[q][kc]), as8(h0f[kc]), aA, 0, 0, 0);
          aB = __builtin_amdgcn_mfma_f32_16x16x32_bf16(as8(wfi[q][kc + 4]), as8(h0f[kc + 4]), aB, 0, 0, 0);
        }
        c1n[q].x = aA[0] + aB[0] + cb[q].x; c1n[q].y = aA[1] + aB[1] + cb[q].y;
        c1n[q].z = aA[2] + aB[2] + cb[q].z; c1n[q].w = aA[3] + aB[3] + cb[q].w;
      }
      asm volatile("s_waitcnt lgkmcnt(0)" ::: "memory");
      __builtin_amdgcn_s_barrier();
      if ((t & 15) == 15 && tid == 0)
        __hip_atomic_store(cf, (u32)(t + 1), __ATOMIC_RELAXED, __HIP_MEMORY_SCOPE_AGENT);
      __builtin_amdgcn_sched_barrier(0);
    };

    for (int t = 0; t < T_; t += 2) {
      cstep(t, c1A, c1B, hb_[0], hb_[1]);
      cstep(t + 1, c1B, c1A, hb_[1], hb_[0]);
    }
  }
}

extern "C" void kernel_launch(void* const* d_in, const int* in_sizes, int n_in,
                              void* d_out, int out_size, void* d_ws, size_t ws_size,
                              hipStream_t stream) {
  (void)in_sizes; (void)n_in; (void)out_size;
  const float* x    = (const float*)d_in[0];
  const float* Wih0 = (const float*)d_in[1];
  const float* Whh0 = (const float*)d_in[2];
  const float* bih0 = (const float*)d_in[3];
  const float* bhh0 = (const float*)d_in[4];
  const float* Wih1 = (const float*)d_in[5];
  const float* Whh1 = (const float*)d_in[6];
  const float* bih1 = (const float*)d_in[7];
  const float* bhh1 = (const float*)d_in[8];
  float* out = (float*)d_out;

  const int TPW = 8;
  const int NWG = (B_ * T_) / (TPW * 16);  // 1024
  const size_t need = 4096 + (size_t)PAIRS * RING * 16 * H_ * 2;  // ~4.2 MB

  pre_mfma<<<dim3(NWG), dim3(256), 0, stream>>>(x, Wih0, bih0, bhh0, out, TPW);
  if (ws_size >= need) {
    u32* flags = (u32*)d_ws;
    u16* ring = (u16*)((char*)d_ws + 4096);
    init_flags<<<dim3(1), dim3(256), 0, stream>>>(flags);
    fused_rec<<<dim3(2 * PAIRS), dim3(512), 0, stream>>>(
        out, Whh0, Wih1, Whh1, bih1, bhh1, out, ring, flags);
  } else {  // fallback: verified round-6 sequence
    rec_mfma<<<dim3(B_ / 16), dim3(512), 0, stream>>>(out, Whh0, out);
    pre_mfma<<<dim3(NWG), dim3(256), 0, stream>>>(out, Wih1, bih1, bhh1, out, TPW);
    rec_mfma<<<dim3(B_ / 16), dim3(512), 0, stream>>>(out, Whh1, out);
  }
}

// Round 8
// 4358.397 us; speedup vs baseline: 1.1095x; 1.1095x over previous
//
#include <hip/hip_runtime.h>
#include <stdint.h>

#define B_ 64
#define T_ 2048
#define H_ 256
#define S_ 64              // chunk length (timesteps)
#define C_ (T_ / S_)       // 32 chunks

typedef unsigned int u32;
typedef unsigned short u16;
typedef __attribute__((ext_vector_type(8))) short short8;
typedef __attribute__((ext_vector_type(4))) float f32x4;

// bf16 tile swizzles (verified rounds 4-6): row-conflict-free ds_read_b128
#define SWZ(row, byte) (((row) * 512) + ((byte) ^ (((row) & 7) << 4)))
// f32 tile (c1): 16 rows x 1024B, same XOR trick -> 8-way-spread b128 access
#define SWZF(row, byte) (((row) * 1024) + ((byte) ^ (((row) & 7) << 4)))

static __device__ __forceinline__ u32 cvtpk(float a, float b) {
  u32 d;
  asm("v_cvt_pk_bf16_f32 %0, %1, %2" : "=v"(d) : "v"(a), "v"(b));
  return d;
}
static __device__ __forceinline__ uint4 pack8(float4 a, float4 b) {
  uint4 r;
  r.x = cvtpk(a.x, a.y); r.y = cvtpk(a.z, a.w);
  r.z = cvtpk(b.x, b.y); r.w = cvtpk(b.z, b.w);
  return r;
}
static __device__ __forceinline__ short8 as8(uint4 v) {
  return __builtin_bit_cast(short8, v);
}
static __device__ __forceinline__ f32x4 mfma4(uint4 a, uint4 b, f32x4 c) {
  return __builtin_amdgcn_mfma_f32_16x16x32_bf16(as8(a), as8(b), c, 0, 0, 0);
}
// 1 - 2*rcp(e^{2x}+1); ~1ulp f32 << bf16 rounding; saturates correctly.
static __device__ __forceinline__ float fast_tanh(float x) {
  float e = __expf(2.0f * x);
  float r = __builtin_amdgcn_rcpf(e + 1.0f);
  return fmaf(-2.0f, r, 1.0f);
}

// Verified A/B fragment loader for mfma_f32_16x16x32_bf16 [m89/m91].
template <int NQ>
static __device__ __forceinline__ void load_wfrag(const float* W, int qbase, int bl,
                                                  int g, uint4 wf[NQ][8]) {
#pragma unroll
  for (int q = 0; q < NQ; ++q) {
    const float* wr = W + (size_t)((qbase + q) * 16 + bl) * H_ + g * 8;
#pragma unroll
    for (int kc = 0; kc < 8; ++kc) {
      float4 a = *(const float4*)(wr + kc * 32);
      float4 b = *(const float4*)(wr + kc * 32 + 4);
      wf[q][kc] = pack8(a, b);
    }
  }
}

// ---------------- layer-0 pre-projection over full T (verified) ----------------
__global__ __launch_bounds__(256, 2) void pre_mfma(const float* X, const float* W,
                                                   const float* bi, const float* bh,
                                                   float* P, int tpw) {
  __shared__ char sb_[2][8192];
  const int tid = threadIdx.x;
  const int lane = tid & 63, wv = tid >> 6;
  const int bl = lane & 15, g = lane >> 4;

  uint4 wf[4][8];
  load_wfrag<4>(W, wv * 4, bl, g, wf);
  float4 bias[4];
#pragma unroll
  for (int q = 0; q < 4; ++q) {
    const int j0 = (wv * 4 + q) * 16 + g * 4;
    float4 a = *(const float4*)(bi + j0);
    float4 c = *(const float4*)(bh + j0);
    bias[q].x = a.x + c.x; bias[q].y = a.y + c.y;
    bias[q].z = a.z + c.z; bias[q].w = a.w + c.w;
  }

  const size_t row0 = (size_t)blockIdx.x * tpw * 16;
  const int sr = tid >> 4, sc = (tid & 15) * 16;
  float4 s0, s1, s2, s3;
  {
    const float4* xs = (const float4*)(X + (row0 + sr) * H_ + sc);
    s0 = xs[0]; s1 = xs[1]; s2 = xs[2]; s3 = xs[3];
  }

  for (int i = 0; i < tpw; ++i) {
    char* sb = sb_[i & 1];
    *(uint4*)(sb + SWZ(sr, sc * 2)) = pack8(s0, s1);
    *(uint4*)(sb + SWZ(sr, sc * 2 + 16)) = pack8(s2, s3);
    __syncthreads();
    if (i + 1 < tpw) {
      const float4* xn = (const float4*)(X + (row0 + (i + 1) * 16 + sr) * H_ + sc);
      s0 = xn[0]; s1 = xn[1]; s2 = xn[2]; s3 = xn[3];
    }
    uint4 hf[8];
#pragma unroll
    for (int kc = 0; kc < 8; ++kc)
      hf[kc] = *(const uint4*)(sb + SWZ(bl, kc * 64 + g * 16));
    f32x4 acc[4];
#pragma unroll
    for (int q = 0; q < 4; ++q) {
      acc[q] = (f32x4){0.f, 0.f, 0.f, 0.f};
#pragma unroll
      for (int kc = 0; kc < 8; ++kc)
        acc[q] = mfma4(wf[q][kc], hf[kc], acc[q]);
    }
#pragma unroll
    for (int q = 0; q < 4; ++q) {
      const int j0 = (wv * 4 + q) * 16 + g * 4;
      float4 o;
      o.x = acc[q][0] + bias[q].x; o.y = acc[q][1] + bias[q].y;
      o.z = acc[q][2] + bias[q].z; o.w = acc[q][3] + bias[q].w;
      *(float4*)(P + (row0 + i * 16 + bl) * H_ + j0) = o;
    }
    __syncthreads();
  }
}

// ---------------- fallback standalone recurrence (round-6, verified) ----------------
__global__ __launch_bounds__(512, 1) void rec_mfma(const float* pre, const float* W,
                                                   float* out) {
  __shared__ char hb_[2][8192];
  const int tid = threadIdx.x;
  const int lane = tid & 63, wv = tid >> 6;
  const int bl = lane & 15, g = lane >> 4;
  const int b0 = blockIdx.x * 16;

  uint4 wf[2][8];
  load_wfrag<2>(W, wv * 2, bl, g, wf);
  {
    uint4 z = make_uint4(0, 0, 0, 0);
    ((uint4*)hb_[0])[tid] = z;
    ((uint4*)hb_[1])[tid] = z;
  }
  const float* prow = pre + (size_t)(b0 + bl) * T_ * H_;
  float* orow = out + (size_t)(b0 + bl) * T_ * H_;
  float4 pr0[2], pr1[2];
#pragma unroll
  for (int q = 0; q < 2; ++q) {
    const int j0 = (wv * 2 + q) * 16 + g * 4;
    pr0[q] = *(const float4*)(prow + 0 * H_ + j0);
    pr1[q] = *(const float4*)(prow + 1 * H_ + j0);
  }
  __syncthreads();

  auto step = [&](int t, float4 (&pr)[2], char* rbuf, char* wbuf) {
    uint4 hf[8];
#pragma unroll
    for (int kc = 0; kc < 8; ++kc)
      hf[kc] = *(const uint4*)(rbuf + SWZ(bl, kc * 64 + g * 16));
    f32x4 accA[2], accB[2];
#pragma unroll
    for (int q = 0; q < 2; ++q) {
      accA[q] = (f32x4){0.f, 0.f, 0.f, 0.f};
      accB[q] = (f32x4){0.f, 0.f, 0.f, 0.f};
#pragma unroll
      for (int kc = 0; kc < 4; ++kc) {
        accA[q] = mfma4(wf[q][kc], hf[kc], accA[q]);
        accB[q] = mfma4(wf[q][kc + 4], hf[kc + 4], accB[q]);
      }
    }
#pragma unroll
    for (int q = 0; q < 2; ++q) {
      const int j0 = (wv * 2 + q) * 16 + g * 4;
      const float* pq = (const float*)&pr[q];
      float v0 = fast_tanh(accA[q][0] + accB[q][0] + pq[0]);
      float v1 = fast_tanh(accA[q][1] + accB[q][1] + pq[1]);
      float v2 = fast_tanh(accA[q][2] + accB[q][2] + pq[2]);
      float v3 = fast_tanh(accA[q][3] + accB[q][3] + pq[3]);
      uint2 hw; hw.x = cvtpk(v0, v1); hw.y = cvtpk(v2, v3);
      *(uint2*)(wbuf + SWZ(bl, j0 * 2)) = hw;
      float4 o; o.x = v0; o.y = v1; o.z = v2; o.w = v3;
      *(float4*)(orow + (size_t)t * H_ + j0) = o;
      if (t + 2 < T_)
        pr[q] = *(const float4*)(prow + (size_t)(t + 2) * H_ + j0);
    }
    asm volatile("s_waitcnt lgkmcnt(0)" ::: "memory");
    __builtin_amdgcn_s_barrier();
    __builtin_amdgcn_sched_barrier(0);
  };

  for (int t = 0; t < T_; t += 2) {
    step(t, pr0, hb_[0], hb_[1]);
    step(t + 1, pr1, hb_[1], hb_[0]);
  }
}

// ---------------- chunk pipeline kernel ----------------
// Kernel c (c = 0..C_): blocks 0-3 run layer-0 recurrence on chunk c
// (h0 -> bf16 ring slot c&1 in ws); blocks 4-7 run layer-1 on chunk c-1
// (4 rec waves + 4 proj waves; proj reads ring slot (c-1)&1 written by the
// PREVIOUS kernel -> coherence via kernel boundary, no cross-WG sync).
// Carries for both recurrences live in ws and are written before the next
// kernel reads them. Fully deterministic; graph-replay safe (every ws byte
// read was written earlier in the same launch sequence).
__global__ __launch_bounds__(512) void chunk_k(
    const float* pre0, float* out, const float* Whh0, const float* Wih1,
    const float* Whh1, const float* bih1, const float* bhh1,
    u16* ring, u16* carry0, u16* carry1, int c) {
  __shared__ __align__(16) char smem[2 * 8192 + 2 * 16384];
  const int tid = threadIdx.x;
  const int lane = tid & 63, wv = tid >> 6;
  const int bl = lane & 15, g = lane >> 4;
  const int bid = blockIdx.x;
  char* hb0 = smem;
  char* hb1 = smem + 8192;
  char* c1b = smem + 16384;  // 2 x 16KB f32 c1 ring (rec1 blocks only)

  if (bid < 4) {
    // ---------- layer-0 recurrence, chunk c ----------
    if (c >= C_) return;
    const int pair = bid;
    uint4 wf[2][8];
    load_wfrag<2>(Whh0, wv * 2, bl, g, wf);
    if (c == 0) {
      uint4 z = make_uint4(0, 0, 0, 0);
      ((uint4*)hb0)[tid] = z;  // 512 x 16B = full 8KB
    } else {
      const u16* cr = carry0 + pair * 16 * H_ + bl * H_;
#pragma unroll
      for (int q = 0; q < 2; ++q) {
        const int j0 = (wv * 2 + q) * 16 + g * 4;
        uint2 hw = *(const uint2*)(cr + j0);
        *(uint2*)(hb0 + SWZ(bl, j0 * 2)) = hw;
      }
    }
    const float* prow = pre0 + (size_t)(pair * 16 + bl) * T_ * H_ + (size_t)c * S_ * H_;
    u16* rch = ring + ((size_t)(c & 1) * S_) * (B_ * H_) + (size_t)(pair * 16 + bl) * H_;
    float4 pr0[2], pr1[2];
#pragma unroll
    for (int q = 0; q < 2; ++q) {
      const int j0 = (wv * 2 + q) * 16 + g * 4;
      pr0[q] = *(const float4*)(prow + 0 * H_ + j0);
      pr1[q] = *(const float4*)(prow + 1 * H_ + j0);
    }
    __syncthreads();

    auto step = [&](int s, float4 (&pr)[2], char* rbuf, char* wbuf) {
      uint4 hf[8];
#pragma unroll
      for (int kc = 0; kc < 8; ++kc)
        hf[kc] = *(const uint4*)(rbuf + SWZ(bl, kc * 64 + g * 16));
      f32x4 accA[2], accB[2];
#pragma unroll
      for (int q = 0; q < 2; ++q) {
        accA[q] = (f32x4){0.f, 0.f, 0.f, 0.f};
        accB[q] = (f32x4){0.f, 0.f, 0.f, 0.f};
#pragma unroll
        for (int kc = 0; kc < 4; ++kc) {
          accA[q] = mfma4(wf[q][kc], hf[kc], accA[q]);
          accB[q] = mfma4(wf[q][kc + 4], hf[kc + 4], accB[q]);
        }
      }
#pragma unroll
      for (int q = 0; q < 2; ++q) {
        const int j0 = (wv * 2 + q) * 16 + g * 4;
        const float* pq = (const float*)&pr[q];
        float v0 = fast_tanh(accA[q][0] + accB[q][0] + pq[0]);
        float v1 = fast_tanh(accA[q][1] + accB[q][1] + pq[1]);
        float v2 = fast_tanh(accA[q][2] + accB[q][2] + pq[2]);
        float v3 = fast_tanh(accA[q][3] + accB[q][3] + pq[3]);
        uint2 hw; hw.x = cvtpk(v0, v1); hw.y = cvtpk(v2, v3);
        *(uint2*)(wbuf + SWZ(bl, j0 * 2)) = hw;                 // h0 for s+1
        *(uint2*)(rch + (size_t)s * (B_ * H_) + j0) = hw;       // h0 -> ring
        if (s + 2 < S_)
          pr[q] = *(const float4*)(prow + (size_t)(s + 2) * H_ + j0);
      }
      asm volatile("s_waitcnt lgkmcnt(0)" ::: "memory");
      __builtin_amdgcn_s_barrier();
      __builtin_amdgcn_sched_barrier(0);
    };
    for (int s = 0; s < S_; s += 2) {
      step(s, pr0, hb0, hb1);
      step(s + 1, pr1, hb1, hb0);
    }
    {  // carry out (final h is in hb0: S_ even; last barrier made it visible)
      u16* cw = carry0 + pair * 16 * H_ + bl * H_;
#pragma unroll
      for (int q = 0; q < 2; ++q) {
        const int j0 = (wv * 2 + q) * 16 + g * 4;
        uint2 hw = *(const uint2*)(hb0 + SWZ(bl, j0 * 2));
        *(uint2*)(cw + j0) = hw;
      }
    }
  } else {
    // ---------- layer-1, chunk c-1: waves 0-3 rec, waves 4-7 proj ----------
    if (c < 1) return;
    const int pair = bid - 4;
    const int ch = c - 1;
    const bool isrec = (wv < 4);
    const int qw = (wv & 3) * 4;  // 4 q-tiles per wave (NQ=4)
    uint4 wf[4][8];
    load_wfrag<4>(isrec ? Whh1 : Wih1, qw, bl, g, wf);
    uint4 h8[8];     // proj: h0 step-tile staging (1-deep, issued 1 step ahead)
    float4 cb[4];    // proj: bias
    const u16* rrd = ring + ((size_t)(ch & 1) * S_) * (B_ * H_) +
                     (size_t)(pair * 16 + bl) * H_ + g * 8;

    if (isrec) {
      if (c == 1) {
        uint4 z = make_uint4(0, 0, 0, 0);
        ((uint4*)hb0)[tid] = z;          // rec waves: tid 0..255
        ((uint4*)hb0)[tid + 256] = z;    // cover full 8KB
      } else {
        const u16* cr = carry1 + pair * 16 * H_ + bl * H_;
#pragma unroll
        for (int q = 0; q < 4; ++q) {
          const int j0 = (qw + q) * 16 + g * 4;
          uint2 hw = *(const uint2*)(cr + j0);
          *(uint2*)(hb0 + SWZ(bl, j0 * 2)) = hw;
        }
      }
    } else {
#pragma unroll
      for (int q = 0; q < 4; ++q) {
        const int j0 = (qw + q) * 16 + g * 4;
        float4 a = *(const float4*)(bih1 + j0);
        float4 b = *(const float4*)(bhh1 + j0);
        cb[q].x = a.x + b.x; cb[q].y = a.y + b.y;
        cb[q].z = a.z + b.z; cb[q].w = a.w + b.w;
      }
      // prologue: c1[0] -> slot 0, then issue h0[1] loads
#pragma unroll
      for (int kc = 0; kc < 8; ++kc)
        h8[kc] = *(const uint4*)(rrd + (size_t)0 * (B_ * H_) + kc * 32);
#pragma unroll
      for (int q = 0; q < 4; ++q) {
        f32x4 pA = (f32x4){0.f, 0.f, 0.f, 0.f}, pB = (f32x4){0.f, 0.f, 0.f, 0.f};
#pragma unroll
        for (int kc = 0; kc < 4; ++kc) {
          pA = mfma4(wf[q][kc], h8[kc], pA);
          pB = mfma4(wf[q][kc + 4], h8[kc + 4], pB);
        }
        const int j0 = (qw + q) * 16 + g * 4;
        float4 o;
        o.x = pA[0] + pB[0] + cb[q].x; o.y = pA[1] + pB[1] + cb[q].y;
        o.z = pA[2] + pB[2] + cb[q].z; o.w = pA[3] + pB[3] + cb[q].w;
        *(float4*)(c1b + SWZF(bl, j0 * 4)) = o;  // slot 0
      }
#pragma unroll
      for (int kc = 0; kc < 8; ++kc)
        h8[kc] = *(const uint4*)(rrd + (size_t)1 * (B_ * H_) + kc * 32);
    }
    __syncthreads();

    float* orow = out + (size_t)(pair * 16 + bl) * T_ * H_ + (size_t)ch * S_ * H_;

    auto step = [&](int s, char* rbuf, char* wbuf) {
      if (isrec) {
        uint4 hf[8];
#pragma unroll
        for (int kc = 0; kc < 8; ++kc)
          hf[kc] = *(const uint4*)(rbuf + SWZ(bl, kc * 64 + g * 16));
        const char* c1r = c1b + (s & 1) * 16384;
        float4 c1v[4];
#pragma unroll
        for (int q = 0; q < 4; ++q)
          c1v[q] = *(const float4*)(c1r + SWZF(bl, ((qw + q) * 16 + g * 4) * 4));
        f32x4 accA[4], accB[4];
#pragma unroll
        for (int q = 0; q < 4; ++q) {
          accA[q] = (f32x4){0.f, 0.f, 0.f, 0.f};
          accB[q] = (f32x4){0.f, 0.f, 0.f, 0.f};
#pragma unroll
          for (int kc = 0; kc < 4; ++kc) {
            accA[q] = mfma4(wf[q][kc], hf[kc], accA[q]);
            accB[q] = mfma4(wf[q][kc + 4], hf[kc + 4], accB[q]);
          }
        }
#pragma unroll
        for (int q = 0; q < 4; ++q) {
          const int j0 = (qw + q) * 16 + g * 4;
          float v0 = fast_tanh(accA[q][0] + accB[q][0] + c1v[q].x);
          float v1 = fast_tanh(accA[q][1] + accB[q][1] + c1v[q].y);
          float v2 = fast_tanh(accA[q][2] + accB[q][2] + c1v[q].z);
          float v3 = fast_tanh(accA[q][3] + accB[q][3] + c1v[q].w);
          uint2 hw; hw.x = cvtpk(v0, v1); hw.y = cvtpk(v2, v3);
          *(uint2*)(wbuf + SWZ(bl, j0 * 2)) = hw;   // h1 for s+1
          float4 o; o.x = v0; o.y = v1; o.z = v2; o.w = v3;
          *(float4*)(orow + (size_t)s * H_ + j0) = o;  // final output
        }
      } else {
        if (s + 1 < S_) {  // consume h8 (h0[s+1]) -> c1[s+1]
          char* c1w = c1b + ((s + 1) & 1) * 16384;
#pragma unroll
          for (int q = 0; q < 4; ++q) {
            f32x4 pA = (f32x4){0.f, 0.f, 0.f, 0.f}, pB = (f32x4){0.f, 0.f, 0.f, 0.f};
#pragma unroll
            for (int kc = 0; kc < 4; ++kc) {
              pA = mfma4(wf[q][kc], h8[kc], pA);
              pB = mfma4(wf[q][kc + 4], h8[kc + 4], pB);
            }
            const int j0 = (qw + q) * 16 + g * 4;
            float4 o;
            o.x = pA[0] + pB[0] + cb[q].x; o.y = pA[1] + pB[1] + cb[q].y;
            o.z = pA[2] + pB[2] + cb[q].z; o.w = pA[3] + pB[3] + cb[q].w;
            *(float4*)(c1w + SWZF(bl, j0 * 4)) = o;
          }
        }
        if (s + 2 < S_) {  // issue h0[s+2]; in flight across the barrier
#pragma unroll
          for (int kc = 0; kc < 8; ++kc)
            h8[kc] = *(const uint4*)(rrd + (size_t)(s + 2) * (B_ * H_) + kc * 32);
        }
      }
      asm volatile("s_waitcnt lgkmcnt(0)" ::: "memory");
      __builtin_amdgcn_s_barrier();
      __builtin_amdgcn_sched_barrier(0);
    };
    for (int s = 0; s < S_; s += 2) {
      step(s, hb0, hb1);
      step(s + 1, hb1, hb0);
    }
    if (isrec) {  // carry out final h1 (in hb0; S_ even)
      u16* cw = carry1 + pair * 16 * H_ + bl * H_;
#pragma unroll
      for (int q = 0; q < 4; ++q) {
        const int j0 = (qw + q) * 16 + g * 4;
        uint2 hw = *(const uint2*)(hb0 + SWZ(bl, j0 * 2));
        *(uint2*)(cw + j0) = hw;
      }
    }
  }
}

extern "C" void kernel_launch(void* const* d_in, const int* in_sizes, int n_in,
                              void* d_out, int out_size, void* d_ws, size_t ws_size,
                              hipStream_t stream) {
  (void)in_sizes; (void)n_in; (void)out_size;
  const float* x    = (const float*)d_in[0];
  const float* Wih0 = (const float*)d_in[1];
  const float* Whh0 = (const float*)d_in[2];
  const float* bih0 = (const float*)d_in[3];
  const float* bhh0 = (const float*)d_in[4];
  const float* Wih1 = (const float*)d_in[5];
  const float* Whh1 = (const float*)d_in[6];
  const float* bih1 = (const float*)d_in[7];
  const float* bhh1 = (const float*)d_in[8];
  float* out = (float*)d_out;

  const int TPW = 8;
  const int NWG = (B_ * T_) / (TPW * 16);  // 1024
  const size_t ring_elems = (size_t)2 * S_ * B_ * H_;     // 2 slots, bf16
  const size_t carry_elems = (size_t)4 * 16 * H_;         // per layer
  const size_t need = (ring_elems + 2 * carry_elems) * sizeof(u16);  // ~4.26 MB

  pre_mfma<<<dim3(NWG), dim3(256), 0, stream>>>(x, Wih0, bih0, bhh0, out, TPW);
  if (ws_size >= need) {
    u16* ring = (u16*)d_ws;
    u16* carry0 = ring + ring_elems;
    u16* carry1 = carry0 + carry_elems;
    for (int c = 0; c <= C_; ++c)
      chunk_k<<<dim3(8), dim3(512), 0, stream>>>(
          out, out, Whh0, Wih1, Whh1, bih1, bhh1, ring, carry0, carry1, c);
  } else {  // fallback: verified round-6 sequence
    rec_mfma<<<dim3(B_ / 16), dim3(512), 0, stream>>>(out, Whh0, out);
    pre_mfma<<<dim3(NWG), dim3(256), 0, stream>>>(out, Wih1, bih1, bhh1, out, TPW);
    rec_mfma<<<dim3(B_ / 16), dim3(512), 0, stream>>>(out, Whh1, out);
  }
}

// Round 9
// 2430.281 us; speedup vs baseline: 1.9897x; 1.7934x over previous
//
#include <hip/hip_runtime.h>
#include <stdint.h>

#define B_ 64
#define T_ 2048
#define H_ 256
#define S_ 64              // chunk length (timesteps)
#define C_ (T_ / S_)       // 32 chunks

typedef unsigned int u32;
typedef unsigned short u16;
typedef __attribute__((ext_vector_type(8))) short short8;
typedef __attribute__((ext_vector_type(4))) float f32x4;

// bf16 tile swizzle (verified rounds 4-8): conflict-free ds_read_b128 at
// (row=lane&15, slice=(lane>>4)*8); same formula on write and read.
#define SWZ(row, byte) (((row) * 512) + ((byte) ^ (((row) & 7) << 4)))

static __device__ __forceinline__ u32 cvtpk(float a, float b) {
  u32 d;
  asm("v_cvt_pk_bf16_f32 %0, %1, %2" : "=v"(d) : "v"(a), "v"(b));
  return d;
}
static __device__ __forceinline__ uint4 pack8(float4 a, float4 b) {
  uint4 r;
  r.x = cvtpk(a.x, a.y); r.y = cvtpk(a.z, a.w);
  r.z = cvtpk(b.x, b.y); r.w = cvtpk(b.z, b.w);
  return r;
}
static __device__ __forceinline__ short8 as8(uint4 v) {
  return __builtin_bit_cast(short8, v);
}
static __device__ __forceinline__ f32x4 mfma4(uint4 a, uint4 b, f32x4 c) {
  return __builtin_amdgcn_mfma_f32_16x16x32_bf16(as8(a), as8(b), c, 0, 0, 0);
}
// 1 - 2*rcp(e^{2x}+1); ~1ulp f32 << bf16 rounding; saturates correctly.
static __device__ __forceinline__ float fast_tanh(float x) {
  float e = __expf(2.0f * x);
  float r = __builtin_amdgcn_rcpf(e + 1.0f);
  return fmaf(-2.0f, r, 1.0f);
}

// Verified A/B fragment loader for mfma_f32_16x16x32_bf16 [m89/m91].
template <int NQ>
static __device__ __forceinline__ void load_wfrag(const float* W, int qbase, int bl,
                                                  int g, uint4 wf[NQ][8]) {
#pragma unroll
  for (int q = 0; q < NQ; ++q) {
    const float* wr = W + (size_t)((qbase + q) * 16 + bl) * H_ + g * 8;
#pragma unroll
    for (int kc = 0; kc < 8; ++kc) {
      float4 a = *(const float4*)(wr + kc * 32);
      float4 b = *(const float4*)(wr + kc * 32 + 4);
      wf[q][kc] = pack8(a, b);
    }
  }
}

// ---------------- layer-0 pre-projection over full T (verified) ----------------
__global__ __launch_bounds__(256, 2) void pre_mfma(const float* X, const float* W,
                                                   const float* bi, const float* bh,
                                                   float* P, int tpw) {
  __shared__ char sb_[2][8192];
  const int tid = threadIdx.x;
  const int lane = tid & 63, wv = tid >> 6;
  const int bl = lane & 15, g = lane >> 4;

  uint4 wf[4][8];
  load_wfrag<4>(W, wv * 4, bl, g, wf);
  float4 bias[4];
#pragma unroll
  for (int q = 0; q < 4; ++q) {
    const int j0 = (wv * 4 + q) * 16 + g * 4;
    float4 a = *(const float4*)(bi + j0);
    float4 c = *(const float4*)(bh + j0);
    bias[q].x = a.x + c.x; bias[q].y = a.y + c.y;
    bias[q].z = a.z + c.z; bias[q].w = a.w + c.w;
  }

  const size_t row0 = (size_t)blockIdx.x * tpw * 16;
  const int sr = tid >> 4, sc = (tid & 15) * 16;
  float4 s0, s1, s2, s3;
  {
    const float4* xs = (const float4*)(X + (row0 + sr) * H_ + sc);
    s0 = xs[0]; s1 = xs[1]; s2 = xs[2]; s3 = xs[3];
  }

  for (int i = 0; i < tpw; ++i) {
    char* sb = sb_[i & 1];
    *(uint4*)(sb + SWZ(sr, sc * 2)) = pack8(s0, s1);
    *(uint4*)(sb + SWZ(sr, sc * 2 + 16)) = pack8(s2, s3);
    __syncthreads();
    if (i + 1 < tpw) {
      const float4* xn = (const float4*)(X + (row0 + (i + 1) * 16 + sr) * H_ + sc);
      s0 = xn[0]; s1 = xn[1]; s2 = xn[2]; s3 = xn[3];
    }
    uint4 hf[8];
#pragma unroll
    for (int kc = 0; kc < 8; ++kc)
      hf[kc] = *(const uint4*)(sb + SWZ(bl, kc * 64 + g * 16));
    f32x4 acc[4];
#pragma unroll
    for (int q = 0; q < 4; ++q) {
      acc[q] = (f32x4){0.f, 0.f, 0.f, 0.f};
#pragma unroll
      for (int kc = 0; kc < 8; ++kc)
        acc[q] = mfma4(wf[q][kc], hf[kc], acc[q]);
    }
#pragma unroll
    for (int q = 0; q < 4; ++q) {
      const int j0 = (wv * 4 + q) * 16 + g * 4;
      float4 o;
      o.x = acc[q][0] + bias[q].x; o.y = acc[q][1] + bias[q].y;
      o.z = acc[q][2] + bias[q].z; o.w = acc[q][3] + bias[q].w;
      *(float4*)(P + (row0 + i * 16 + bl) * H_ + j0) = o;
    }
    __syncthreads();
  }
}

// ---------------- fallback standalone recurrence (round-6, verified) ----------------
__global__ __launch_bounds__(512, 1) void rec_mfma(const float* pre, const float* W,
                                                   float* out) {
  __shared__ char hb_[2][8192];
  const int tid = threadIdx.x;
  const int lane = tid & 63, wv = tid >> 6;
  const int bl = lane & 15, g = lane >> 4;
  const int b0 = blockIdx.x * 16;

  uint4 wf[2][8];
  load_wfrag<2>(W, wv * 2, bl, g, wf);
  {
    uint4 z = make_uint4(0, 0, 0, 0);
    ((uint4*)hb_[0])[tid] = z;
    ((uint4*)hb_[1])[tid] = z;
  }
  const float* prow = pre + (size_t)(b0 + bl) * T_ * H_;
  float* orow = out + (size_t)(b0 + bl) * T_ * H_;
  float4 pr0[2], pr1[2];
#pragma unroll
  for (int q = 0; q < 2; ++q) {
    const int j0 = (wv * 2 + q) * 16 + g * 4;
    pr0[q] = *(const float4*)(prow + 0 * H_ + j0);
    pr1[q] = *(const float4*)(prow + 1 * H_ + j0);
  }
  __syncthreads();

  auto step = [&](int t, float4 (&pr)[2], char* rbuf, char* wbuf) {
    uint4 hf[8];
#pragma unroll
    for (int kc = 0; kc < 8; ++kc)
      hf[kc] = *(const uint4*)(rbuf + SWZ(bl, kc * 64 + g * 16));
    f32x4 accA[2], accB[2];
#pragma unroll
    for (int q = 0; q < 2; ++q) {
      accA[q] = (f32x4){0.f, 0.f, 0.f, 0.f};
      accB[q] = (f32x4){0.f, 0.f, 0.f, 0.f};
#pragma unroll
      for (int kc = 0; kc < 4; ++kc) {
        accA[q] = mfma4(wf[q][kc], hf[kc], accA[q]);
        accB[q] = mfma4(wf[q][kc + 4], hf[kc + 4], accB[q]);
      }
    }
#pragma unroll
    for (int q = 0; q < 2; ++q) {
      const int j0 = (wv * 2 + q) * 16 + g * 4;
      const float* pq = (const float*)&pr[q];
      float v0 = fast_tanh(accA[q][0] + accB[q][0] + pq[0]);
      float v1 = fast_tanh(accA[q][1] + accB[q][1] + pq[1]);
      float v2 = fast_tanh(accA[q][2] + accB[q][2] + pq[2]);
      float v3 = fast_tanh(accA[q][3] + accB[q][3] + pq[3]);
      uint2 hw; hw.x = cvtpk(v0, v1); hw.y = cvtpk(v2, v3);
      *(uint2*)(wbuf + SWZ(bl, j0 * 2)) = hw;
      float4 o; o.x = v0; o.y = v1; o.z = v2; o.w = v3;
      *(float4*)(orow + (size_t)t * H_ + j0) = o;
      if (t + 2 < T_)
        pr[q] = *(const float4*)(prow + (size_t)(t + 2) * H_ + j0);
    }
    asm volatile("s_waitcnt lgkmcnt(0)" ::: "memory");
    __builtin_amdgcn_s_barrier();
    __builtin_amdgcn_sched_barrier(0);
  };

  for (int t = 0; t < T_; t += 2) {
    step(t, pr0, hb_[0], hb_[1]);
    step(t + 1, pr1, hb_[1], hb_[0]);
  }
}

// ---------------- 3-stage chunk pipeline kernel ----------------
// Kernel c: blocks 0-3 rec0(chunk c) -> h0 bf16 ring; blocks 4-7 proj1
// (chunk c-1): c1 = Wih1*h0 + b -> f32 into d_out[chunk c-1] (its pre0 was
// consumed at kernel c-1); blocks 8-11 rec1(chunk c-2): round-6 in-place
// recurrence on d_out (reads c1 with 2-step lead, overwrites with h1).
// All cross-stage data crosses a kernel boundary -> coherent (G16); every
// ws/d_out byte read was written earlier in the same launch sequence ->
// graph-replay safe and deterministic.
__global__ __launch_bounds__(512, 1) void chunk2_k(
    float* dout, const float* Whh0, const float* Wih1, const float* Whh1,
    const float* bih1, const float* bhh1,
    u16* ring, u16* carry0, u16* carry1, int c) {
  __shared__ __align__(16) char smem[2 * 8192];
  const int tid = threadIdx.x;
  const int lane = tid & 63, wv = tid >> 6;
  const int bl = lane & 15, g = lane >> 4;
  const int bid = blockIdx.x;
  char* sb0 = smem;
  char* sb1 = smem + 8192;

  if (bid < 4) {
    // ---------- rec0: layer-0 recurrence, chunk c ----------
    if (c >= C_) return;
    const int pair = bid;
    uint4 wf[2][8];
    load_wfrag<2>(Whh0, wv * 2, bl, g, wf);
    if (c == 0) {
      uint4 z = make_uint4(0, 0, 0, 0);
      ((uint4*)sb0)[tid] = z;  // 512 x 16B = full 8KB
    } else {
      const u16* cr = carry0 + pair * 16 * H_ + bl * H_;
#pragma unroll
      for (int q = 0; q < 2; ++q) {
        const int j0 = (wv * 2 + q) * 16 + g * 4;
        uint2 hw = *(const uint2*)(cr + j0);
        *(uint2*)(sb0 + SWZ(bl, j0 * 2)) = hw;
      }
    }
    const float* prow = dout + (size_t)(pair * 16 + bl) * T_ * H_ + (size_t)c * S_ * H_;
    u16* rch = ring + ((size_t)(c & 1) * S_) * (B_ * H_) + (size_t)(pair * 16 + bl) * H_;
    float4 pr0[2], pr1[2];
#pragma unroll
    for (int q = 0; q < 2; ++q) {
      const int j0 = (wv * 2 + q) * 16 + g * 4;
      pr0[q] = *(const float4*)(prow + 0 * H_ + j0);
      pr1[q] = *(const float4*)(prow + 1 * H_ + j0);
    }
    __syncthreads();

    auto step = [&](int s, float4 (&pr)[2], char* rbuf, char* wbuf) {
      uint4 hf[8];
#pragma unroll
      for (int kc = 0; kc < 8; ++kc)
        hf[kc] = *(const uint4*)(rbuf + SWZ(bl, kc * 64 + g * 16));
      f32x4 accA[2], accB[2];
#pragma unroll
      for (int q = 0; q < 2; ++q) {
        accA[q] = (f32x4){0.f, 0.f, 0.f, 0.f};
        accB[q] = (f32x4){0.f, 0.f, 0.f, 0.f};
#pragma unroll
        for (int kc = 0; kc < 4; ++kc) {
          accA[q] = mfma4(wf[q][kc], hf[kc], accA[q]);
          accB[q] = mfma4(wf[q][kc + 4], hf[kc + 4], accB[q]);
        }
      }
#pragma unroll
      for (int q = 0; q < 2; ++q) {
        const int j0 = (wv * 2 + q) * 16 + g * 4;
        const float* pq = (const float*)&pr[q];
        float v0 = fast_tanh(accA[q][0] + accB[q][0] + pq[0]);
        float v1 = fast_tanh(accA[q][1] + accB[q][1] + pq[1]);
        float v2 = fast_tanh(accA[q][2] + accB[q][2] + pq[2]);
        float v3 = fast_tanh(accA[q][3] + accB[q][3] + pq[3]);
        uint2 hw; hw.x = cvtpk(v0, v1); hw.y = cvtpk(v2, v3);
        *(uint2*)(wbuf + SWZ(bl, j0 * 2)) = hw;             // h0 for s+1
        *(uint2*)(rch + (size_t)s * (B_ * H_) + j0) = hw;   // h0 -> ring
        if (s + 2 < S_)
          pr[q] = *(const float4*)(prow + (size_t)(s + 2) * H_ + j0);
      }
      asm volatile("s_waitcnt lgkmcnt(0)" ::: "memory");
      __builtin_amdgcn_s_barrier();
      __builtin_amdgcn_sched_barrier(0);
    };
    for (int s = 0; s < S_; s += 2) {
      step(s, pr0, sb0, sb1);
      step(s + 1, pr1, sb1, sb0);
    }
    {  // carry out (final h in sb0; S_ even; last barrier made it visible)
      u16* cw = carry0 + pair * 16 * H_ + bl * H_;
#pragma unroll
      for (int q = 0; q < 2; ++q) {
        const int j0 = (wv * 2 + q) * 16 + g * 4;
        uint2 hw = *(const uint2*)(sb0 + SWZ(bl, j0 * 2));
        *(uint2*)(cw + j0) = hw;
      }
    }
  } else if (bid < 8) {
    // ---------- proj1: c1 = Wih1 . h0 + bias, chunk c-1 (throughput GEMM) ----------
    if (c < 1 || c > C_) return;
    const int pair = bid - 4;
    const int ch = c - 1;
    uint4 wf[2][8];
    load_wfrag<2>(Wih1, wv * 2, bl, g, wf);
    float4 cb[2];
#pragma unroll
    for (int q = 0; q < 2; ++q) {
      const int j0 = (wv * 2 + q) * 16 + g * 4;
      float4 a = *(const float4*)(bih1 + j0);
      float4 b = *(const float4*)(bhh1 + j0);
      cb[q].x = a.x + b.x; cb[q].y = a.y + b.y;
      cb[q].z = a.z + b.z; cb[q].w = a.w + b.w;
    }
    const u16* rbase2 = ring + ((size_t)(ch & 1) * S_) * (B_ * H_) + (size_t)pair * 16 * H_;
    const int sr = tid >> 5, scb = (tid & 31) * 16;  // stage: 16 rows x 512B
    uint4 v = *(const uint4*)(rbase2 + 0 * (B_ * H_) + (size_t)sr * H_ + (tid & 31) * 8);

    for (int s = 0; s < S_; ++s) {
      char* sb = (s & 1) ? sb1 : sb0;
      *(uint4*)(sb + SWZ(sr, scb)) = v;  // stage current (bf16 passthrough)
      __syncthreads();
      if (s + 1 < S_)
        v = *(const uint4*)(rbase2 + (size_t)(s + 1) * (B_ * H_) + (size_t)sr * H_ + (tid & 31) * 8);
      uint4 hf[8];
#pragma unroll
      for (int kc = 0; kc < 8; ++kc)
        hf[kc] = *(const uint4*)(sb + SWZ(bl, kc * 64 + g * 16));
      f32x4 acc[2];
#pragma unroll
      for (int q = 0; q < 2; ++q) {
        acc[q] = (f32x4){0.f, 0.f, 0.f, 0.f};
#pragma unroll
        for (int kc = 0; kc < 8; ++kc)
          acc[q] = mfma4(wf[q][kc], hf[kc], acc[q]);
      }
      float* od = dout + (size_t)(pair * 16 + bl) * T_ * H_ + (size_t)(ch * S_ + s) * H_;
#pragma unroll
      for (int q = 0; q < 2; ++q) {
        const int j0 = (wv * 2 + q) * 16 + g * 4;
        float4 o;
        o.x = acc[q][0] + cb[q].x; o.y = acc[q][1] + cb[q].y;
        o.z = acc[q][2] + cb[q].z; o.w = acc[q][3] + cb[q].w;
        *(float4*)(od + j0) = o;
      }
      __syncthreads();  // all reads done before s+2 overwrites this buffer
    }
  } else {
    // ---------- rec1: layer-1 recurrence, chunk c-2, in-place on d_out ----------
    if (c < 2) return;
    const int pair = bid - 8;
    const int ch = c - 2;
    uint4 wf[2][8];
    load_wfrag<2>(Whh1, wv * 2, bl, g, wf);
    if (ch == 0) {
      uint4 z = make_uint4(0, 0, 0, 0);
      ((uint4*)sb0)[tid] = z;
    } else {
      const u16* cr = carry1 + pair * 16 * H_ + bl * H_;
#pragma unroll
      for (int q = 0; q < 2; ++q) {
        const int j0 = (wv * 2 + q) * 16 + g * 4;
        uint2 hw = *(const uint2*)(cr + j0);
        *(uint2*)(sb0 + SWZ(bl, j0 * 2)) = hw;
      }
    }
    float* prow = dout + (size_t)(pair * 16 + bl) * T_ * H_ + (size_t)ch * S_ * H_;
    float4 pr0[2], pr1[2];
#pragma unroll
    for (int q = 0; q < 2; ++q) {
      const int j0 = (wv * 2 + q) * 16 + g * 4;
      pr0[q] = *(const float4*)(prow + 0 * H_ + j0);
      pr1[q] = *(const float4*)(prow + 1 * H_ + j0);
    }
    __syncthreads();

    auto step = [&](int s, float4 (&pr)[2], char* rbuf, char* wbuf) {
      uint4 hf[8];
#pragma unroll
      for (int kc = 0; kc < 8; ++kc)
        hf[kc] = *(const uint4*)(rbuf + SWZ(bl, kc * 64 + g * 16));
      f32x4 accA[2], accB[2];
#pragma unroll
      for (int q = 0; q < 2; ++q) {
        accA[q] = (f32x4){0.f, 0.f, 0.f, 0.f};
        accB[q] = (f32x4){0.f, 0.f, 0.f, 0.f};
#pragma unroll
        for (int kc = 0; kc < 4; ++kc) {
          accA[q] = mfma4(wf[q][kc], hf[kc], accA[q]);
          accB[q] = mfma4(wf[q][kc + 4], hf[kc + 4], accB[q]);
        }
      }
#pragma unroll
      for (int q = 0; q < 2; ++q) {
        const int j0 = (wv * 2 + q) * 16 + g * 4;
        const float* pq = (const float*)&pr[q];
        float v0 = fast_tanh(accA[q][0] + accB[q][0] + pq[0]);
        float v1 = fast_tanh(accA[q][1] + accB[q][1] + pq[1]);
        float v2 = fast_tanh(accA[q][2] + accB[q][2] + pq[2]);
        float v3 = fast_tanh(accA[q][3] + accB[q][3] + pq[3]);
        uint2 hw; hw.x = cvtpk(v0, v1); hw.y = cvtpk(v2, v3);
        *(uint2*)(wbuf + SWZ(bl, j0 * 2)) = hw;         // h1 for s+1
        float4 o; o.x = v0; o.y = v1; o.z = v2; o.w = v3;
        *(float4*)(prow + (size_t)s * H_ + j0) = o;     // in-place h1 out
        if (s + 2 < S_)
          pr[q] = *(const float4*)(prow + (size_t)(s + 2) * H_ + j0);  // c1 lead-2
      }
      asm volatile("s_waitcnt lgkmcnt(0)" ::: "memory");
      __builtin_amdgcn_s_barrier();
      __builtin_amdgcn_sched_barrier(0);
    };
    for (int s = 0; s < S_; s += 2) {
      step(s, pr0, sb0, sb1);
      step(s + 1, pr1, sb1, sb0);
    }
    {  // carry out final h1
      u16* cw = carry1 + pair * 16 * H_ + bl * H_;
#pragma unroll
      for (int q = 0; q < 2; ++q) {
        const int j0 = (wv * 2 + q) * 16 + g * 4;
        uint2 hw = *(const uint2*)(sb0 + SWZ(bl, j0 * 2));
        *(uint2*)(cw + j0) = hw;
      }
    }
  }
}

extern "C" void kernel_launch(void* const* d_in, const int* in_sizes, int n_in,
                              void* d_out, int out_size, void* d_ws, size_t ws_size,
                              hipStream_t stream) {
  (void)in_sizes; (void)n_in; (void)out_size;
  const float* x    = (const float*)d_in[0];
  const float* Wih0 = (const float*)d_in[1];
  const float* Whh0 = (const float*)d_in[2];
  const float* bih0 = (const float*)d_in[3];
  const float* bhh0 = (const float*)d_in[4];
  const float* Wih1 = (const float*)d_in[5];
  const float* Whh1 = (const float*)d_in[6];
  const float* bih1 = (const float*)d_in[7];
  const float* bhh1 = (const float*)d_in[8];
  float* out = (float*)d_out;

  const int TPW = 8;
  const int NWG = (B_ * T_) / (TPW * 16);  // 1024
  const size_t ring_elems = (size_t)2 * S_ * B_ * H_;     // 2 slots, bf16
  const size_t carry_elems = (size_t)4 * 16 * H_;         // per layer
  const size_t need = (ring_elems + 2 * carry_elems) * sizeof(u16);  // ~4.26 MB

  pre_mfma<<<dim3(NWG), dim3(256), 0, stream>>>(x, Wih0, bih0, bhh0, out, TPW);
  if (ws_size >= need) {
    u16* ring = (u16*)d_ws;
    u16* carry0 = ring + ring_elems;
    u16* carry1 = carry0 + carry_elems;
    for (int c = 0; c <= C_ + 1; ++c)
      chunk2_k<<<dim3(12), dim3(512), 0, stream>>>(
          out, Whh0, Wih1, Whh1, bih1, bhh1, ring, carry0, carry1, c);
  } else {  // fallback: verified round-6 sequence
    rec_mfma<<<dim3(B_ / 16), dim3(512), 0, stream>>>(out, Whh0, out);
    pre_mfma<<<dim3(NWG), dim3(256), 0, stream>>>(out, Wih1, bih1, bhh1, out, TPW);
    rec_mfma<<<dim3(B_ / 16), dim3(512), 0, stream>>>(out, Whh1, out);
  }
}